// Round 2
// baseline (387.115 us; speedup 1.0000x reference)
//
#include <hip/hip_runtime.h>

// ---------------------------------------------------------------------------
// BaseWindowAttention on MI355X (gfx950)
// x:[2,256,256,256]f32, w_qkv:[256,768]f32, pos_emb:[15,15]f32,
// w_out:[256,256]f32, b_out:[256]f32, rel_idx:[64,64,2]i32
// out:[2,256,256,256]f32
//
// Pipeline:
//  prep:     w_qkv^T, w_out^T -> bf16 (ws), biasP[lane][64] f32 (ws)
//  qkv_gemm: qkv[131072][768] bf16 (ws)  = x @ w_qkv     (MFMA 16x16x32 bf16)
//  attn:     per-window attention (swapped-QK^T in-register softmax);
//            ao bf16 packed into bytes [512,1024) of each 1KB d_out row
//  out_gemm: out = ao @ w_out + b_out
// ---------------------------------------------------------------------------

typedef __bf16 bf16_t;
typedef __bf16 bf16x8 __attribute__((ext_vector_type(8)));
typedef __bf16 bf16x4 __attribute__((ext_vector_type(4)));
typedef float  f32x4  __attribute__((ext_vector_type(4)));

#define MFMA_BF16(a, b, c) __builtin_amdgcn_mfma_f32_16x16x32_bf16((a), (b), (c), 0, 0, 0)
#define SM_SCALE 0.17677669529663687f  // 32^-0.5

// ws layout (bytes)
#define WQKVT_OFF 0u          // bf16 [768][256]
#define WOUTT_OFF 393216u     // bf16 [256][256]
#define BIASP_OFF 524288u     // f32  [64 lanes][64]  (pre-permuted)
#define QKV_OFF   540672u     // bf16 [131072][768]

__device__ __forceinline__ void gload16(const void* g, void* l) {
    // async global->LDS, 16B per lane. LDS dest = wave-uniform base + lane*16.
    __builtin_amdgcn_global_load_lds(
        (const __attribute__((address_space(1))) unsigned int*)g,
        (__attribute__((address_space(3))) unsigned int*)l,
        16, 0, 0);
}

// ---------------------------------------------------------------------------
__global__ __launch_bounds__(256) void prep_kernel(
    const float* __restrict__ w_qkv, const float* __restrict__ w_out,
    const float* __restrict__ pos_emb, const int* __restrict__ rel_idx,
    bf16_t* __restrict__ wqkvT, bf16_t* __restrict__ woutT,
    float* __restrict__ biasP)
{
    int idx = blockIdx.x * 256 + threadIdx.x;
    if (idx < 196608) {                 // wqkvT[n][k] = w_qkv[k][n]
        int n = idx >> 8, k = idx & 255;
        wqkvT[idx] = (bf16_t)w_qkv[k * 768 + n];
    } else if (idx < 262144) {          // woutT[n][k] = w_out[k][n]
        int t = idx - 196608;
        int n = t >> 8, k = t & 255;
        woutT[t] = (bf16_t)w_out[k * 256 + n];
    } else if (idx < 266240) {          // biasP[lane][e]: per-lane MFMA layout
        int t = idx - 262144;
        int lane = t >> 6, e = t & 63;
        int ni = e >> 4, mi = (e >> 2) & 3, rg = e & 3;
        int i = 16 * ni + (lane & 15);          // query index
        int j = 16 * mi + 4 * (lane >> 4) + rg; // key index
        int i0 = rel_idx[(i * 64 + j) * 2 + 0];
        int i1 = rel_idx[(i * 64 + j) * 2 + 1];
        biasP[t] = pos_emb[i0 * 15 + i1];
    }
}

// ---------------------------------------------------------------------------
// qkv GEMM: C[M=131072][N=768] = A[M][256](f32) * B^T[N][256](bf16), C bf16.
// 128x128 tile, 4 waves (each 64x64), BK=32, single-buffer 2-barrier loop.
__global__ __launch_bounds__(256) void qkv_gemm_kernel(
    const float* __restrict__ x, const bf16_t* __restrict__ wT,
    bf16_t* __restrict__ qkv)
{
    __shared__ __align__(16) float  As[128 * 32];   // 16KB f32
    __shared__ __align__(16) bf16_t Bs[128 * 32];   // 8KB bf16

    const int tid = threadIdx.x;
    const int b = blockIdx.x;
    const int bm = b & 1023, bn = b >> 10;          // bm-major for x locality
    const int m0 = bm << 7, n0 = bn << 7;
    const int lane = tid & 63, wv = tid >> 6;
    const int g = lane >> 4, c = lane & 15;
    const int wm = wv >> 1, wn = wv & 1;

    f32x4 acc[4][4];
    f32x4 z4 = {0.f, 0.f, 0.f, 0.f};
#pragma unroll
    for (int i = 0; i < 4; ++i)
#pragma unroll
        for (int j = 0; j < 4; ++j) acc[i][j] = z4;

    const f32x4* Asf = (const f32x4*)As;
    const f32x4* Bsf = (const f32x4*)Bs;

    for (int ks = 0; ks < 8; ++ks) {
        const int k0 = ks << 5;
#pragma unroll
        for (int i = 0; i < 4; ++i) {
            int q = i * 256 + tid;
            int row = q >> 3;
            int pl = (q & 7) ^ (row & 7);
            gload16(x + (m0 + row) * 256 + k0 + pl * 4,
                    (char*)As + (i * 256 + wv * 64) * 16);
        }
#pragma unroll
        for (int i = 0; i < 2; ++i) {
            int q = i * 256 + tid;
            int row = q >> 2;
            int pl = (q & 3) ^ (row & 3);
            gload16(wT + (n0 + row) * 256 + k0 + pl * 8,
                    (char*)Bs + (i * 256 + wv * 64) * 16);
        }
        __syncthreads();

        bf16x8 af[4], bfr[4];
#pragma unroll
        for (int mi = 0; mi < 4; ++mi) {
            int r = wm * 64 + mi * 16 + c;
            f32x4 a0 = Asf[r * 8 + ((2 * g)     ^ (r & 7))];
            f32x4 a1 = Asf[r * 8 + ((2 * g + 1) ^ (r & 7))];
            bf16x8 t;
            t[0] = (bf16_t)a0[0]; t[1] = (bf16_t)a0[1];
            t[2] = (bf16_t)a0[2]; t[3] = (bf16_t)a0[3];
            t[4] = (bf16_t)a1[0]; t[5] = (bf16_t)a1[1];
            t[6] = (bf16_t)a1[2]; t[7] = (bf16_t)a1[3];
            af[mi] = t;
        }
#pragma unroll
        for (int ni = 0; ni < 4; ++ni) {
            int r = wn * 64 + ni * 16 + c;
            f32x4 t = Bsf[r * 4 + (g ^ (r & 3))];
            bfr[ni] = __builtin_bit_cast(bf16x8, t);
        }
#pragma unroll
        for (int mi = 0; mi < 4; ++mi)
#pragma unroll
            for (int ni = 0; ni < 4; ++ni)
                acc[mi][ni] = MFMA_BF16(af[mi], bfr[ni], acc[mi][ni]);
        __syncthreads();
    }

    // epilogue: D layout col=lane&15, row=4*(lane>>4)+reg
#pragma unroll
    for (int mi = 0; mi < 4; ++mi)
#pragma unroll
        for (int ni = 0; ni < 4; ++ni)
#pragma unroll
            for (int rg = 0; rg < 4; ++rg) {
                int grow = m0 + wm * 64 + mi * 16 + 4 * g + rg;
                int gcol = n0 + wn * 64 + ni * 16 + c;
                qkv[(size_t)grow * 768 + gcol] = (bf16_t)acc[mi][ni][rg];
            }
}

// ---------------------------------------------------------------------------
// Window attention v2. Block = one (l, window), 4 waves, 2 heads/wave.
// Swapped QK^T: s[mi][ni] = mfma(K-frag, Q-frag) -> lane (c,g) holds
// S[q=16ni+c][k=16mi+4g+rg]. Softmax row-reduce = 2 shfl_xor (over g).
// P normalized in-register, packed b64 into a 2KB double-buffered tile;
// PV per ni (2 ds_read_b128 + 4 MFMA). Output staged via LDS (reuses V
// buffer) -> 4x16B coalesced global stores per head.
__global__ __launch_bounds__(256, 4) void attn_kernel(
    const bf16_t* __restrict__ qkv, const float* __restrict__ biasP,
    float* __restrict__ aout)
{
    __shared__ __align__(16) bf16_t P_s[4][2048];   // 4KB/wave (2 x 2KB dbuf)
    __shared__ __align__(16) bf16_t Vt_s[4][2048];  // 4KB/wave (Vt, then O)

    const int tid = threadIdx.x;
    const int lane = tid & 63, wv = tid >> 6;
    const int g = lane >> 4, c = lane & 15;
    const int b = blockIdx.x;
    const int l = b >> 10, win = b & 1023;
    const int whi = win >> 5, wwi = win & 31;
    const int rbase = l * 65536 + whi * 2048 + wwi * 8;  // token row base

    bf16_t* Pw = P_s[wv];
    bf16_t* Vw = Vt_s[wv];
    const float* bp = biasP + lane * 64;
    f32x4 z4 = {0.f, 0.f, 0.f, 0.f};

    for (int hh = 0; hh < 2; ++hh) {
        const int h = wv * 2 + hh;

        // K (A-frag) / Q (B-frag) / V rows straight from global, 16B per lane.
        bf16x8 qf[4], kf[4], vv[4];
#pragma unroll
        for (int mi = 0; mi < 4; ++mi) {
            int t = mi * 16 + c;
            size_t r = (size_t)(rbase + (t >> 3) * 256 + (t & 7));
            qf[mi] = *(const bf16x8*)(qkv + r * 768 + h * 32 + g * 8);
            kf[mi] = *(const bf16x8*)(qkv + r * 768 + 256 + h * 32 + g * 8);
        }
        {
            int t = lane;
            size_t r = (size_t)(rbase + (t >> 3) * 256 + (t & 7));
#pragma unroll
            for (int d0 = 0; d0 < 4; ++d0)
                vv[d0] = *(const bf16x8*)(qkv + r * 768 + 512 + h * 32 + d0 * 8);
        }

        // S^T tiles: s[mi][ni] row=k-part, col=q-part
        f32x4 s[4][4];
#pragma unroll
        for (int i = 0; i < 4; ++i)
#pragma unroll
            for (int j = 0; j < 4; ++j) s[i][j] = z4;
#pragma unroll
        for (int mi = 0; mi < 4; ++mi)
#pragma unroll
            for (int ni = 0; ni < 4; ++ni)
                s[mi][ni] = MFMA_BF16(kf[mi], qf[ni], s[mi][ni]);

        // V -> Vt LDS (transposed, swizzled): Vt[dh][tok]
        {
            int t = lane;
#pragma unroll
            for (int d0 = 0; d0 < 4; ++d0) {
                bf16x8 v = vv[d0];
#pragma unroll
                for (int j = 0; j < 8; ++j) {
                    int dh = d0 * 8 + j;
                    Vw[dh * 64 + ((((t >> 3) ^ (dh & 7)) << 3) | (t & 7))] = v[j];
                }
            }
        }
        // hoist V B-fragments (Vt dead afterwards -> buffer reused for O)
        bf16x8 vb[2][2];
#pragma unroll
        for (int ks = 0; ks < 2; ++ks)
#pragma unroll
            for (int nj = 0; nj < 2; ++nj) {
                int dh = nj * 16 + c;
                vb[ks][nj] = *(const bf16x8*)(Vw + dh * 64 + (((4 * ks + g) ^ (dh & 7)) << 3));
            }

        // per-ni: softmax (in-register) -> P tile -> PV -> stage O rows
#pragma unroll
        for (int ni = 0; ni < 4; ++ni) {
            float mx = -1e30f;
            f32x4 v[4];
#pragma unroll
            for (int mi = 0; mi < 4; ++mi) {
                f32x4 bb = *(const f32x4*)(bp + ni * 16 + mi * 4);
#pragma unroll
                for (int rg = 0; rg < 4; ++rg) {
                    float t = fmaf(s[mi][ni][rg], SM_SCALE, bb[rg]);
                    v[mi][rg] = t;
                    mx = fmaxf(mx, t);
                }
            }
            mx = fmaxf(mx, __shfl_xor(mx, 16));
            mx = fmaxf(mx, __shfl_xor(mx, 32));
            float sm = 0.f;
#pragma unroll
            for (int mi = 0; mi < 4; ++mi)
#pragma unroll
                for (int rg = 0; rg < 4; ++rg) {
                    float p = __expf(v[mi][rg] - mx);
                    v[mi][rg] = p;
                    sm += p;
                }
            sm += __shfl_xor(sm, 16);
            sm += __shfl_xor(sm, 32);
            float inv = 1.0f / sm;

            bf16_t* Pl = Pw + (ni & 1) * 1024;   // double-buffered 2KB tile
#pragma unroll
            for (int mi = 0; mi < 4; ++mi) {
                bf16x4 pk;
#pragma unroll
                for (int rg = 0; rg < 4; ++rg) pk[rg] = (bf16_t)(v[mi][rg] * inv);
                *(bf16x4*)(Pl + c * 64 + (((2 * mi + (g >> 1)) ^ (c & 7)) << 3) + 4 * (g & 1)) = pk;
            }

            f32x4 o0 = z4, o1 = z4;
#pragma unroll
            for (int ks = 0; ks < 2; ++ks) {
                bf16x8 pa = *(const bf16x8*)(Pl + c * 64 + (((4 * ks + g) ^ (c & 7)) << 3));
                o0 = MFMA_BF16(pa, vb[ks][0], o0);
                o1 = MFMA_BF16(pa, vb[ks][1], o1);
            }
            // stage O rows 16ni..16ni+15 into Vw (Ot[tok][dh], chunk-swizzled)
#pragma unroll
            for (int rg = 0; rg < 4; ++rg) {
                int tok = 16 * ni + 4 * g + rg;
                int dh0 = c;            // nj = 0
                int dh1 = 16 + c;       // nj = 1
                Vw[tok * 32 + ((((dh0 >> 3) ^ (tok & 3))) << 3) + (dh0 & 7)] = (bf16_t)o0[rg];
                Vw[tok * 32 + ((((dh1 >> 3) ^ (tok & 3))) << 3) + (dh1 & 7)] = (bf16_t)o1[rg];
            }
        }

        // coalesced read-back + 16B global stores
#pragma unroll
        for (int i = 0; i < 4; ++i) {
            int ch = i * 64 + lane;
            int tok = ch >> 2, cc = ch & 3;
            bf16x8 val = *(const bf16x8*)(Vw + tok * 32 + ((cc ^ (tok & 3)) << 3));
            size_t r = (size_t)(rbase + (tok >> 3) * 256 + (tok & 7));
            *(bf16x8*)((char*)aout + r * 1024 + 512 + h * 64 + cc * 16) = val;
        }
    }
}

// ---------------------------------------------------------------------------
// out GEMM: out[M][256] = ao[M][256](bf16, packed in out rows) @ w_out + b.
__global__ __launch_bounds__(512) void out_gemm_kernel(
    const bf16_t* __restrict__ wT, const float* __restrict__ b_out,
    float* out)
{
    __shared__ __align__(16) bf16_t As[128 * 32];   // 8KB
    __shared__ __align__(16) bf16_t Bs[256 * 32];   // 16KB

    const int tid = threadIdx.x;
    const int lane = tid & 63, wv = tid >> 6;
    const int g = lane >> 4, c = lane & 15;
    const int wm = wv >> 2, wn = wv & 3;
    const int m0 = blockIdx.x << 7;

    f32x4 acc[4][4];
    f32x4 z4 = {0.f, 0.f, 0.f, 0.f};
#pragma unroll
    for (int i = 0; i < 4; ++i)
#pragma unroll
        for (int j = 0; j < 4; ++j) acc[i][j] = z4;

    const f32x4* Asf = (const f32x4*)As;
    const f32x4* Bsf = (const f32x4*)Bs;

    for (int ks = 0; ks < 8; ++ks) {
        {   // stage A: 512 chunks, 1/thread
            int q = tid;
            int row = q >> 2;
            int pl = (q & 3) ^ (row & 3);
            gload16((const char*)out + (size_t)(m0 + row) * 1024 + 512 + ks * 64 + pl * 16,
                    (char*)As + wv * 1024);
        }
#pragma unroll
        for (int i = 0; i < 2; ++i) {   // stage B: 1024 chunks, 2/thread
            int q = i * 512 + tid;
            int row = q >> 2;
            int pl = (q & 3) ^ (row & 3);
            gload16(wT + row * 256 + ks * 32 + pl * 8,
                    (char*)Bs + (i * 512 + wv * 64) * 16);
        }
        __syncthreads();

        bf16x8 af[4], bfr[4];
#pragma unroll
        for (int mi = 0; mi < 4; ++mi) {
            int r = wm * 64 + mi * 16 + c;
            f32x4 t = Asf[r * 4 + (g ^ (r & 3))];
            af[mi] = __builtin_bit_cast(bf16x8, t);
        }
#pragma unroll
        for (int ni = 0; ni < 4; ++ni) {
            int r = wn * 64 + ni * 16 + c;
            f32x4 t = Bsf[r * 4 + (g ^ (r & 3))];
            bfr[ni] = __builtin_bit_cast(bf16x8, t);
        }
#pragma unroll
        for (int mi = 0; mi < 4; ++mi)
#pragma unroll
            for (int ni = 0; ni < 4; ++ni)
                acc[mi][ni] = MFMA_BF16(af[mi], bfr[ni], acc[mi][ni]);
        __syncthreads();
    }

#pragma unroll
    for (int ni = 0; ni < 4; ++ni) {
        int gcol = wn * 64 + ni * 16 + c;
        float bo = b_out[gcol];
#pragma unroll
        for (int mi = 0; mi < 4; ++mi)
#pragma unroll
            for (int rg = 0; rg < 4; ++rg) {
                int grow = m0 + wm * 64 + mi * 16 + 4 * g + rg;
                out[(size_t)grow * 256 + gcol] = acc[mi][ni][rg] + bo;
            }
    }
}

// ---------------------------------------------------------------------------
extern "C" void kernel_launch(void* const* d_in, const int* in_sizes, int n_in,
                              void* d_out, int out_size, void* d_ws, size_t ws_size,
                              hipStream_t stream) {
    const float* x       = (const float*)d_in[0];
    const float* w_qkv   = (const float*)d_in[1];
    const float* pos_emb = (const float*)d_in[2];
    const float* w_out   = (const float*)d_in[3];
    const float* b_out   = (const float*)d_in[4];
    const int*   rel_idx = (const int*)d_in[5];

    char* ws = (char*)d_ws;
    bf16_t* wqkvT = (bf16_t*)(ws + WQKVT_OFF);
    bf16_t* woutT = (bf16_t*)(ws + WOUTT_OFF);
    float*  biasP = (float*)(ws + BIASP_OFF);
    bf16_t* qkv   = (bf16_t*)(ws + QKV_OFF);   // needs ~192.5MB of ws
    float*  out   = (float*)d_out;

    prep_kernel<<<1040, 256, 0, stream>>>(w_qkv, w_out, pos_emb, rel_idx,
                                          wqkvT, woutT, biasP);
    qkv_gemm_kernel<<<6144, 256, 0, stream>>>(x, wqkvT, qkv);
    attn_kernel<<<2048, 256, 0, stream>>>(qkv, biasP, out);
    out_gemm_kernel<<<1024, 512, 0, stream>>>(woutT, b_out, out);
}

// Round 3
// 286.402 us; speedup vs baseline: 1.3516x; 1.3516x over previous
//
#include <hip/hip_runtime.h>

// ---------------------------------------------------------------------------
// BaseWindowAttention on MI355X (gfx950)
// x:[2,256,256,256]f32, w_qkv:[256,768]f32, pos_emb:[15,15]f32,
// w_out:[256,256]f32, b_out:[256]f32, rel_idx:[64,64,2]i32
// out:[2,256,256,256]f32
//
// Pipeline:
//  xconv:    x -> bf16, packed into bytes [0,512) of each 1KB d_out row
//  prep:     w_qkv^T, w_out^T -> bf16 (ws), biasP[lane][64] f32 (ws)
//  qkv_gemm: qkv[131072][768] bf16 (ws) = xbf @ w_qkv  (MFMA 16x16x32 bf16)
//  attn:     per-(window,head) wave attention; ao bf16 -> bytes [512,1024)
//            of each 1KB d_out row (disjoint from xbf region)
//  out_gemm: out = ao @ w_out + b_out (block covers full N=256; reads its
//            own rows' ao before overwriting them)
// ---------------------------------------------------------------------------

typedef __bf16 bf16_t;
typedef __bf16 bf16x8 __attribute__((ext_vector_type(8)));
typedef __bf16 bf16x4 __attribute__((ext_vector_type(4)));
typedef float  f32x4  __attribute__((ext_vector_type(4)));

#define MFMA_BF16(a, b, c) __builtin_amdgcn_mfma_f32_16x16x32_bf16((a), (b), (c), 0, 0, 0)
#define SM_SCALE 0.17677669529663687f  // 32^-0.5

// ws layout (bytes)
#define WQKVT_OFF 0u          // bf16 [768][256]
#define WOUTT_OFF 393216u     // bf16 [256][256]
#define BIASP_OFF 524288u     // f32  [64 lanes][64]  (pre-permuted)
#define QKV_OFF   540672u     // bf16 [131072][768]

__device__ __forceinline__ void gload16(const void* g, void* l) {
    // async global->LDS, 16B per lane. LDS dest = wave-uniform base + lane*16.
    __builtin_amdgcn_global_load_lds(
        (const __attribute__((address_space(1))) unsigned int*)g,
        (__attribute__((address_space(3))) unsigned int*)l,
        16, 0, 0);
}

// ---------------------------------------------------------------------------
// x (f32) -> bf16 rows packed into first 512B of each 1KB d_out row.
__global__ __launch_bounds__(256) void xconv_kernel(
    const float* __restrict__ x, float* __restrict__ aout)
{
    int i = blockIdx.x * 256 + threadIdx.x;   // 4194304 chunks of 8 elems
    int row = i >> 5, cc = i & 31;
    const f32x4* xs = (const f32x4*)(x + (size_t)row * 256 + cc * 8);
    f32x4 a = xs[0], b = xs[1];
    bf16x8 t;
    t[0] = (bf16_t)a[0]; t[1] = (bf16_t)a[1];
    t[2] = (bf16_t)a[2]; t[3] = (bf16_t)a[3];
    t[4] = (bf16_t)b[0]; t[5] = (bf16_t)b[1];
    t[6] = (bf16_t)b[2]; t[7] = (bf16_t)b[3];
    *(bf16x8*)((char*)aout + (size_t)row * 1024 + cc * 16) = t;
}

// ---------------------------------------------------------------------------
__global__ __launch_bounds__(256) void prep_kernel(
    const float* __restrict__ w_qkv, const float* __restrict__ w_out,
    const float* __restrict__ pos_emb, const int* __restrict__ rel_idx,
    bf16_t* __restrict__ wqkvT, bf16_t* __restrict__ woutT,
    float* __restrict__ biasP)
{
    int idx = blockIdx.x * 256 + threadIdx.x;
    if (idx < 196608) {                 // wqkvT[n][k] = w_qkv[k][n]
        int n = idx >> 8, k = idx & 255;
        wqkvT[idx] = (bf16_t)w_qkv[k * 768 + n];
    } else if (idx < 262144) {          // woutT[n][k] = w_out[k][n]
        int t = idx - 196608;
        int n = t >> 8, k = t & 255;
        woutT[t] = (bf16_t)w_out[k * 256 + n];
    } else if (idx < 266240) {          // biasP[lane][e]: per-lane MFMA layout
        int t = idx - 262144;
        int lane = t >> 6, e = t & 63;
        int ni = e >> 4, mi = (e >> 2) & 3, rg = e & 3;
        int i = 16 * ni + (lane & 15);          // query index
        int j = 16 * mi + 4 * (lane >> 4) + rg; // key index
        int i0 = rel_idx[(i * 64 + j) * 2 + 0];
        int i1 = rel_idx[(i * 64 + j) * 2 + 1];
        biasP[t] = pos_emb[i0 * 15 + i1];
    }
}

// ---------------------------------------------------------------------------
// qkv GEMM: C[M=131072][N=768] = A[M][256](bf16, in d_out rows) * B^T (bf16).
// 128x128 tile, 4 waves (each 64x64), BK=32, single-buffer 2-barrier loop.
// No in-loop cvt: both operands bf16, ds_read_b128 -> MFMA directly.
__global__ __launch_bounds__(256) void qkv_gemm_kernel(
    const float* __restrict__ aout, const bf16_t* __restrict__ wT,
    bf16_t* __restrict__ qkv)
{
    __shared__ __align__(16) bf16_t As[128 * 32];   // 8KB
    __shared__ __align__(16) bf16_t Bs[128 * 32];   // 8KB

    const int tid = threadIdx.x;
    const int b = blockIdx.x;
    const int bm = b & 1023, bn = b >> 10;          // bm-major for x locality
    const int m0 = bm << 7, n0 = bn << 7;
    const int lane = tid & 63, wv = tid >> 6;
    const int g = lane >> 4, c = lane & 15;
    const int wm = wv >> 1, wn = wv & 1;

    f32x4 acc[4][4];
    f32x4 z4 = {0.f, 0.f, 0.f, 0.f};
#pragma unroll
    for (int i = 0; i < 4; ++i)
#pragma unroll
        for (int j = 0; j < 4; ++j) acc[i][j] = z4;

    const f32x4* Asf = (const f32x4*)As;
    const f32x4* Bsf = (const f32x4*)Bs;

    for (int ks = 0; ks < 8; ++ks) {
#pragma unroll
        for (int i = 0; i < 2; ++i) {   // stage A: 512 x 16B chunks (bf16)
            int q = i * 256 + tid;
            int row = q >> 2;
            int pl = (q & 3) ^ (row & 3);
            gload16((const char*)aout + (size_t)(m0 + row) * 1024 + ks * 64 + pl * 16,
                    (char*)As + (i * 256 + wv * 64) * 16);
        }
#pragma unroll
        for (int i = 0; i < 2; ++i) {   // stage B: 512 x 16B chunks (bf16)
            int q = i * 256 + tid;
            int row = q >> 2;
            int pl = (q & 3) ^ (row & 3);
            gload16(wT + (n0 + row) * 256 + ks * 32 + pl * 8,
                    (char*)Bs + (i * 256 + wv * 64) * 16);
        }
        __syncthreads();

        bf16x8 af[4], bfr[4];
#pragma unroll
        for (int mi = 0; mi < 4; ++mi) {
            int r = wm * 64 + mi * 16 + c;
            f32x4 t = Asf[r * 4 + (g ^ (r & 3))];
            af[mi] = __builtin_bit_cast(bf16x8, t);
        }
#pragma unroll
        for (int ni = 0; ni < 4; ++ni) {
            int r = wn * 64 + ni * 16 + c;
            f32x4 t = Bsf[r * 4 + (g ^ (r & 3))];
            bfr[ni] = __builtin_bit_cast(bf16x8, t);
        }
#pragma unroll
        for (int mi = 0; mi < 4; ++mi)
#pragma unroll
            for (int ni = 0; ni < 4; ++ni)
                acc[mi][ni] = MFMA_BF16(af[mi], bfr[ni], acc[mi][ni]);
        __syncthreads();
    }

    // epilogue: D layout col=lane&15, row=4*(lane>>4)+reg
#pragma unroll
    for (int mi = 0; mi < 4; ++mi)
#pragma unroll
        for (int ni = 0; ni < 4; ++ni)
#pragma unroll
            for (int rg = 0; rg < 4; ++rg) {
                int grow = m0 + wm * 64 + mi * 16 + 4 * g + rg;
                int gcol = n0 + wn * 64 + ni * 16 + c;
                qkv[(size_t)grow * 768 + gcol] = (bf16_t)acc[mi][ni][rg];
            }
}

// ---------------------------------------------------------------------------
// Window attention v3. Grid 4096 = 2048 windows x 2 head-groups; 4 waves;
// wave = one (window, head). Per-ni (16-query slice) dataflow keeps peak
// live state ~110 VGPR: 4 QK^T MFMA -> in-register softmax (2 shfl_xor) ->
// normalized P (b64, swizzled LDS) -> PV (2 b128 + 4 MFMA) -> direct global
// scalar stores. No O staging (round-2's bank-conflict source).
__global__ __launch_bounds__(256, 3) void attn_kernel(
    const bf16_t* __restrict__ qkv, const float* __restrict__ biasP,
    float* __restrict__ aout)
{
    __shared__ __align__(16) bf16_t P_s[4][2048];   // 4KB/wave (2x2KB dbuf)
    __shared__ __align__(16) bf16_t Vt_s[4][2048];  // 4KB/wave

    const int tid = threadIdx.x;
    const int lane = tid & 63, wv = tid >> 6;
    const int g = lane >> 4, c = lane & 15;
    const int b = blockIdx.x;
    const int win = b >> 1;                   // 0..2047
    const int h = (b & 1) * 4 + wv;           // head 0..7
    const int rbase = (win >> 10) * 65536 + ((win >> 5) & 31) * 2048 + (win & 31) * 8;

    bf16_t* Pw = P_s[wv];
    bf16_t* Vw = Vt_s[wv];
    const float* bp = biasP + lane * 64;
    f32x4 z4 = {0.f, 0.f, 0.f, 0.f};

    // K (A-frag) / Q (B-frag): 16B per lane straight from global.
    bf16x8 qf[4], kf[4];
#pragma unroll
    for (int mi = 0; mi < 4; ++mi) {
        int t = mi * 16 + c;
        size_t r = (size_t)(rbase + (t >> 3) * 256 + (t & 7));
        const bf16_t* rowp = qkv + r * 768 + h * 32;
        qf[mi] = *(const bf16x8*)(rowp + g * 8);
        kf[mi] = *(const bf16x8*)(rowp + 256 + g * 8);
    }
    // V -> Vt LDS (transposed, swizzled): Vt[dh][tok]
    {
        int t = lane;
        size_t r = (size_t)(rbase + (t >> 3) * 256 + (t & 7));
        const bf16_t* rowp = qkv + r * 768 + 512 + h * 32;
#pragma unroll
        for (int d0 = 0; d0 < 4; ++d0) {
            bf16x8 v = *(const bf16x8*)(rowp + d0 * 8);
#pragma unroll
            for (int j = 0; j < 8; ++j) {
                int dh = d0 * 8 + j;
                Vw[dh * 64 + ((((t >> 3) ^ (dh & 7)) << 3) | (t & 7))] = v[j];
            }
        }
    }
    // hoist V B-fragments (conflict-free b128)
    bf16x8 vb[2][2];
#pragma unroll
    for (int ks = 0; ks < 2; ++ks)
#pragma unroll
        for (int nj = 0; nj < 2; ++nj) {
            int dh = nj * 16 + c;
            vb[ks][nj] = *(const bf16x8*)(Vw + dh * 64 + (((4 * ks + g) ^ (dh & 7)) << 3));
        }

    // per-ni: QK^T -> softmax -> P tile -> PV -> direct global stores
#pragma unroll
    for (int ni = 0; ni < 4; ++ni) {
        f32x4 s[4];
#pragma unroll
        for (int mi = 0; mi < 4; ++mi)
            s[mi] = MFMA_BF16(kf[mi], qf[ni], z4);

        float mx = -1e30f;
#pragma unroll
        for (int mi = 0; mi < 4; ++mi) {
            f32x4 bb = *(const f32x4*)(bp + ni * 16 + mi * 4);
#pragma unroll
            for (int rg = 0; rg < 4; ++rg) {
                float t = fmaf(s[mi][rg], SM_SCALE, bb[rg]);
                s[mi][rg] = t;
                mx = fmaxf(mx, t);
            }
        }
        mx = fmaxf(mx, __shfl_xor(mx, 16));
        mx = fmaxf(mx, __shfl_xor(mx, 32));
        float sm = 0.f;
#pragma unroll
        for (int mi = 0; mi < 4; ++mi)
#pragma unroll
            for (int rg = 0; rg < 4; ++rg) {
                float p = __expf(s[mi][rg] - mx);
                s[mi][rg] = p;
                sm += p;
            }
        sm += __shfl_xor(sm, 16);
        sm += __shfl_xor(sm, 32);
        float inv = 1.0f / sm;

        bf16_t* Pl = Pw + (ni & 1) * 1024;   // 2KB dbuf tile
#pragma unroll
        for (int mi = 0; mi < 4; ++mi) {
            bf16x4 pk;
#pragma unroll
            for (int rg = 0; rg < 4; ++rg) pk[rg] = (bf16_t)(s[mi][rg] * inv);
            *(bf16x4*)(Pl + c * 64 + (((2 * mi + (g >> 1)) ^ (c & 7)) << 3) + 4 * (g & 1)) = pk;
        }

        f32x4 o0 = z4, o1 = z4;
#pragma unroll
        for (int ks = 0; ks < 2; ++ks) {
            bf16x8 pa = *(const bf16x8*)(Pl + c * 64 + (((4 * ks + g) ^ (c & 7)) << 3));
            o0 = MFMA_BF16(pa, vb[ks][0], o0);
            o1 = MFMA_BF16(pa, vb[ks][1], o1);
        }
        // direct stores: O[q=16ni+4g+rg][dh=c | 16+c]
#pragma unroll
        for (int rg = 0; rg < 4; ++rg) {
            int tok = 16 * ni + 4 * g + rg;
            size_t r = (size_t)(rbase + (tok >> 3) * 256 + (tok & 7));
            bf16_t* ao = (bf16_t*)((char*)aout + r * 1024 + 512 + h * 64);
            ao[c]      = (bf16_t)o0[rg];
            ao[16 + c] = (bf16_t)o1[rg];
        }
    }
}

// ---------------------------------------------------------------------------
// out GEMM: out[M][256] = ao[M][256](bf16, packed in out rows) @ w_out + b.
__global__ __launch_bounds__(512) void out_gemm_kernel(
    const bf16_t* __restrict__ wT, const float* __restrict__ b_out,
    float* out)
{
    __shared__ __align__(16) bf16_t As[128 * 32];   // 8KB
    __shared__ __align__(16) bf16_t Bs[256 * 32];   // 16KB

    const int tid = threadIdx.x;
    const int lane = tid & 63, wv = tid >> 6;
    const int g = lane >> 4, c = lane & 15;
    const int wm = wv >> 2, wn = wv & 3;
    const int m0 = blockIdx.x << 7;

    f32x4 acc[4][4];
    f32x4 z4 = {0.f, 0.f, 0.f, 0.f};
#pragma unroll
    for (int i = 0; i < 4; ++i)
#pragma unroll
        for (int j = 0; j < 4; ++j) acc[i][j] = z4;

    const f32x4* Asf = (const f32x4*)As;
    const f32x4* Bsf = (const f32x4*)Bs;

    for (int ks = 0; ks < 8; ++ks) {
        {   // stage A: 512 chunks, 1/thread
            int q = tid;
            int row = q >> 2;
            int pl = (q & 3) ^ (row & 3);
            gload16((const char*)out + (size_t)(m0 + row) * 1024 + 512 + ks * 64 + pl * 16,
                    (char*)As + wv * 1024);
        }
#pragma unroll
        for (int i = 0; i < 2; ++i) {   // stage B: 1024 chunks, 2/thread
            int q = i * 512 + tid;
            int row = q >> 2;
            int pl = (q & 3) ^ (row & 3);
            gload16(wT + row * 256 + ks * 32 + pl * 8,
                    (char*)Bs + (i * 512 + wv * 64) * 16);
        }
        __syncthreads();

        bf16x8 af[4], bfr[4];
#pragma unroll
        for (int mi = 0; mi < 4; ++mi) {
            int r = wm * 64 + mi * 16 + c;
            f32x4 t = Asf[r * 4 + (g ^ (r & 3))];
            af[mi] = __builtin_bit_cast(bf16x8, t);
        }
#pragma unroll
        for (int ni = 0; ni < 4; ++ni) {
            int r = wn * 64 + ni * 16 + c;
            f32x4 t = Bsf[r * 4 + (g ^ (r & 3))];
            bfr[ni] = __builtin_bit_cast(bf16x8, t);
        }
#pragma unroll
        for (int mi = 0; mi < 4; ++mi)
#pragma unroll
            for (int ni = 0; ni < 4; ++ni)
                acc[mi][ni] = MFMA_BF16(af[mi], bfr[ni], acc[mi][ni]);
        __syncthreads();
    }

#pragma unroll
    for (int ni = 0; ni < 4; ++ni) {
        int gcol = wn * 64 + ni * 16 + c;
        float bo = b_out[gcol];
#pragma unroll
        for (int mi = 0; mi < 4; ++mi)
#pragma unroll
            for (int rg = 0; rg < 4; ++rg) {
                int grow = m0 + wm * 64 + mi * 16 + 4 * g + rg;
                out[(size_t)grow * 256 + gcol] = acc[mi][ni][rg] + bo;
            }
    }
}

// ---------------------------------------------------------------------------
extern "C" void kernel_launch(void* const* d_in, const int* in_sizes, int n_in,
                              void* d_out, int out_size, void* d_ws, size_t ws_size,
                              hipStream_t stream) {
    const float* x       = (const float*)d_in[0];
    const float* w_qkv   = (const float*)d_in[1];
    const float* pos_emb = (const float*)d_in[2];
    const float* w_out   = (const float*)d_in[3];
    const float* b_out   = (const float*)d_in[4];
    const int*   rel_idx = (const int*)d_in[5];

    char* ws = (char*)d_ws;
    bf16_t* wqkvT = (bf16_t*)(ws + WQKVT_OFF);
    bf16_t* woutT = (bf16_t*)(ws + WOUTT_OFF);
    float*  biasP = (float*)(ws + BIASP_OFF);
    bf16_t* qkv   = (bf16_t*)(ws + QKV_OFF);   // needs ~192.5MB of ws
    float*  out   = (float*)d_out;

    xconv_kernel<<<16384, 256, 0, stream>>>(x, out);
    prep_kernel<<<1040, 256, 0, stream>>>(w_qkv, w_out, pos_emb, rel_idx,
                                          wqkvT, woutT, biasP);
    qkv_gemm_kernel<<<6144, 256, 0, stream>>>(out, wqkvT, qkv);
    attn_kernel<<<4096, 256, 0, stream>>>(qkv, biasP, out);
    out_gemm_kernel<<<1024, 512, 0, stream>>>(woutT, b_out, out);
}

// Round 4
// 224.993 us; speedup vs baseline: 1.7206x; 1.2729x over previous
//
#include <hip/hip_runtime.h>

// ---------------------------------------------------------------------------
// BaseWindowAttention on MI355X (gfx950) — fused 3-kernel pipeline
// x:[2,256,256,256]f32, w_qkv:[256,768]f32, pos_emb:[15,15]f32,
// w_out:[256,256]f32, b_out:[256]f32, rel_idx:[64,64,2]i32
// out:[2,256,256,256]f32
//
//  prep:     w_qkv^T, w_out^T -> bf16 (ws), biasP[lane][64] f32 (ws)
//  qkvproj:  fused x->bf16 + qkv GEMM. Block = 128 rows; x staged ONCE into
//            a chunk-XOR'd 64KB LDS tile, reused across all 6 column-tiles.
//  attn_out: fused window attention + output projection. Block = 1 window,
//            8 waves (1 head each). PV computed as O^T = V^T P^T so the
//            accumulator is dh-major per lane -> b64 row-major ao LDS writes;
//            GEMM2 reads ao as A-frags (conflict-free b128) and writes final
//            out f32 directly.
// ---------------------------------------------------------------------------

typedef __bf16 bf16_t;
typedef __bf16 bf16x8 __attribute__((ext_vector_type(8)));
typedef __bf16 bf16x4 __attribute__((ext_vector_type(4)));
typedef float  f32x4  __attribute__((ext_vector_type(4)));

#define MFMA_BF16(a, b, c) __builtin_amdgcn_mfma_f32_16x16x32_bf16((a), (b), (c), 0, 0, 0)
#define SM_SCALE 0.17677669529663687f  // 32^-0.5

// ws layout (bytes)
#define WQKVT_OFF 0u          // bf16 [768][256]
#define WOUTT_OFF 393216u     // bf16 [256][256]
#define BIASP_OFF 524288u     // f32  [64 lanes][64]  (pre-permuted)
#define QKV_OFF   540672u     // bf16 [131072][768]

__device__ __forceinline__ void gload16(const void* g, void* l) {
    __builtin_amdgcn_global_load_lds(
        (const __attribute__((address_space(1))) unsigned int*)g,
        (__attribute__((address_space(3))) unsigned int*)l,
        16, 0, 0);
}

// ---------------------------------------------------------------------------
__global__ __launch_bounds__(256) void prep_kernel(
    const float* __restrict__ w_qkv, const float* __restrict__ w_out,
    const float* __restrict__ pos_emb, const int* __restrict__ rel_idx,
    bf16_t* __restrict__ wqkvT, bf16_t* __restrict__ woutT,
    float* __restrict__ biasP)
{
    int idx = blockIdx.x * 256 + threadIdx.x;
    if (idx < 196608) {                 // wqkvT[n][k] = w_qkv[k][n]
        int n = idx >> 8, k = idx & 255;
        wqkvT[idx] = (bf16_t)w_qkv[k * 768 + n];
    } else if (idx < 262144) {          // woutT[n][k] = w_out[k][n]
        int t = idx - 196608;
        int n = t >> 8, k = t & 255;
        woutT[t] = (bf16_t)w_out[k * 256 + n];
    } else if (idx < 266240) {          // biasP[lane][e]: per-lane MFMA layout
        int t = idx - 262144;
        int lane = t >> 6, e = t & 63;
        int ni = e >> 4, mi = (e >> 2) & 3, rg = e & 3;
        int i = 16 * ni + (lane & 15);          // query index
        int j = 16 * mi + 4 * (lane >> 4) + rg; // key index
        int i0 = rel_idx[(i * 64 + j) * 2 + 0];
        int i1 = rel_idx[(i * 64 + j) * 2 + 1];
        biasP[t] = pos_emb[i0 * 15 + i1];
    }
}

// ---------------------------------------------------------------------------
// Fused x-convert + qkv GEMM.
// C[M=131072][N=768] = bf16(x)[M][256] @ wT^T, C bf16.
// Block = 128 rows (grid 1024), 4 waves (2x2 of 64x64), BK=32.
// A resident in LDS for the whole block: 128x256 bf16, 16B chunks stored at
// slot = chunk ^ (row&31). B staged 8KB per (bn,ks) via global_load_lds.
__global__ __launch_bounds__(256, 2) void qkvproj_kernel(
    const float* __restrict__ x, const bf16_t* __restrict__ wT,
    bf16_t* __restrict__ qkv)
{
    __shared__ __align__(16) bf16_t A_s[128 * 256];   // 64KB
    __shared__ __align__(16) bf16_t B_s[128 * 32];    // 8KB

    const int tid = threadIdx.x;
    const int lane = tid & 63, wv = tid >> 6;
    const int g = lane >> 4, c = lane & 15;
    const int wm = wv >> 1, wn = wv & 1;
    const int m0 = blockIdx.x << 7;

    // phase 0: x (f32) -> bf16 into A_s, coalesced 32B/lane, XOR-chunked.
#pragma unroll
    for (int jj = 0; jj < 16; ++jj) {
        int q = jj * 512 + tid * 2;          // f32x4-chunk index (8192 total)
        int row = q >> 6;
        int ci = (q & 63) >> 1;              // 16B bf16-chunk 0..31
        const f32x4* xp = (const f32x4*)(x + (size_t)(m0 + row) * 256 + (q & 63) * 4);
        f32x4 a = xp[0], b = xp[1];
        bf16x8 t;
        t[0] = (bf16_t)a[0]; t[1] = (bf16_t)a[1];
        t[2] = (bf16_t)a[2]; t[3] = (bf16_t)a[3];
        t[4] = (bf16_t)b[0]; t[5] = (bf16_t)b[1];
        t[6] = (bf16_t)b[2]; t[7] = (bf16_t)b[3];
        *(bf16x8*)(A_s + row * 256 + ((ci ^ (row & 31)) << 3)) = t;
    }
    __syncthreads();

    const f32x4* Bsf = (const f32x4*)B_s;
    f32x4 z4 = {0.f, 0.f, 0.f, 0.f};

    for (int bn = 0; bn < 6; ++bn) {
        const int n0 = bn << 7;
        f32x4 acc[4][4];
#pragma unroll
        for (int i = 0; i < 4; ++i)
#pragma unroll
            for (int j = 0; j < 4; ++j) acc[i][j] = z4;

        for (int ks = 0; ks < 8; ++ks) {
#pragma unroll
            for (int i = 0; i < 2; ++i) {   // stage B: 512 x 16B chunks
                int q = i * 256 + tid;
                int row = q >> 2;
                int pl = (q & 3) ^ (row & 3);
                gload16(wT + (n0 + row) * 256 + ks * 32 + pl * 8,
                        (char*)B_s + (i * 256 + wv * 64) * 16);
            }
            __syncthreads();

            bf16x8 af[4], bfr[4];
#pragma unroll
            for (int mi = 0; mi < 4; ++mi) {
                int r = wm * 64 + mi * 16 + c;
                af[mi] = *(const bf16x8*)(A_s + r * 256 + (((4 * ks + g) ^ (r & 31)) << 3));
            }
#pragma unroll
            for (int ni = 0; ni < 4; ++ni) {
                int r2 = wn * 64 + ni * 16 + c;
                f32x4 t = Bsf[r2 * 4 + (g ^ (r2 & 3))];
                bfr[ni] = __builtin_bit_cast(bf16x8, t);
            }
#pragma unroll
            for (int mi = 0; mi < 4; ++mi)
#pragma unroll
                for (int ni = 0; ni < 4; ++ni)
                    acc[mi][ni] = MFMA_BF16(af[mi], bfr[ni], acc[mi][ni]);
            __syncthreads();
        }

        // epilogue for this column tile
#pragma unroll
        for (int mi = 0; mi < 4; ++mi)
#pragma unroll
            for (int ni = 0; ni < 4; ++ni)
#pragma unroll
                for (int rg = 0; rg < 4; ++rg) {
                    int grow = m0 + wm * 64 + mi * 16 + 4 * g + rg;
                    int gcol = n0 + wn * 64 + ni * 16 + c;
                    qkv[(size_t)grow * 768 + gcol] = (bf16_t)acc[mi][ni][rg];
                }
    }
}

// ---------------------------------------------------------------------------
// Fused window attention + output projection. Grid 2048 (one per window),
// 512 threads = 8 waves = 8 heads. Attn per wave is the round-3 structure
// (swapped QK^T, in-register softmax). PV swapped too: O^T = V^T P^T via
// mfma(vb_frag, pa_frag) -> per-lane 4 consecutive dh -> b64 row-major ao
// writes (chunk-XOR). GEMM2: out = ao @ w_out + b, A-frags from ao LDS.
__global__ __launch_bounds__(512, 2) void attn_out_kernel(
    const bf16_t* __restrict__ qkv, const float* __restrict__ biasP,
    const bf16_t* __restrict__ woutT, const float* __restrict__ b_out,
    float* __restrict__ out)
{
    __shared__ __align__(16) bf16_t P_s[8][2048];    // 4KB/wave (2x2KB)
    __shared__ __align__(16) bf16_t Vt_s[8][2048];   // 4KB/wave
    __shared__ __align__(16) bf16_t AO_s[64 * 256];  // 32KB

    const int tid = threadIdx.x;
    const int lane = tid & 63, wv = tid >> 6;
    const int g = lane >> 4, c = lane & 15;
    const int b = blockIdx.x;
    const int h = wv;
    const int rbase = (b >> 10) * 65536 + ((b >> 5) & 31) * 2048 + (b & 31) * 8;

    bf16_t* Pw = P_s[wv];
    bf16_t* Vw = Vt_s[wv];
    const float* bp = biasP + lane * 64;
    f32x4 z4 = {0.f, 0.f, 0.f, 0.f};

    // K (A-frag) / Q (B-frag): 16B per lane straight from global.
    bf16x8 qf[4], kf[4];
#pragma unroll
    for (int mi = 0; mi < 4; ++mi) {
        int t = mi * 16 + c;
        size_t r = (size_t)(rbase + (t >> 3) * 256 + (t & 7));
        const bf16_t* rowp = qkv + r * 768 + h * 32;
        qf[mi] = *(const bf16x8*)(rowp + g * 8);
        kf[mi] = *(const bf16x8*)(rowp + 256 + g * 8);
    }
    // V -> Vt LDS (transposed, swizzled): Vt[dh][tok]
    {
        int t = lane;
        size_t r = (size_t)(rbase + (t >> 3) * 256 + (t & 7));
        const bf16_t* rowp = qkv + r * 768 + 512 + h * 32;
#pragma unroll
        for (int d0 = 0; d0 < 4; ++d0) {
            bf16x8 v = *(const bf16x8*)(rowp + d0 * 8);
#pragma unroll
            for (int j = 0; j < 8; ++j) {
                int dh = d0 * 8 + j;
                Vw[dh * 64 + ((((t >> 3) ^ (dh & 7)) << 3) | (t & 7))] = v[j];
            }
        }
    }
    // V^T A-fragments: lane(c,g) -> V^T[dh=16mi+c][tok 8(4ks+g)/8..]
    bf16x8 vbA[2][2];
#pragma unroll
    for (int ks = 0; ks < 2; ++ks)
#pragma unroll
        for (int mi = 0; mi < 2; ++mi) {
            int dh = mi * 16 + c;
            vbA[ks][mi] = *(const bf16x8*)(Vw + dh * 64 + (((4 * ks + g) ^ (dh & 7)) << 3));
        }

    // per-ni: QK^T -> softmax -> P tile -> O^T = V^T P^T -> ao LDS
#pragma unroll
    for (int ni = 0; ni < 4; ++ni) {
        f32x4 s[4];
#pragma unroll
        for (int mi = 0; mi < 4; ++mi)
            s[mi] = MFMA_BF16(kf[mi], qf[ni], z4);

        float mx = -1e30f;
#pragma unroll
        for (int mi = 0; mi < 4; ++mi) {
            f32x4 bb = *(const f32x4*)(bp + ni * 16 + mi * 4);
#pragma unroll
            for (int rg = 0; rg < 4; ++rg) {
                float t = fmaf(s[mi][rg], SM_SCALE, bb[rg]);
                s[mi][rg] = t;
                mx = fmaxf(mx, t);
            }
        }
        mx = fmaxf(mx, __shfl_xor(mx, 16));
        mx = fmaxf(mx, __shfl_xor(mx, 32));
        float sm = 0.f;
#pragma unroll
        for (int mi = 0; mi < 4; ++mi)
#pragma unroll
            for (int rg = 0; rg < 4; ++rg) {
                float p = __expf(s[mi][rg] - mx);
                s[mi][rg] = p;
                sm += p;
            }
        sm += __shfl_xor(sm, 16);
        sm += __shfl_xor(sm, 32);
        float inv = 1.0f / sm;

        bf16_t* Pl = Pw + (ni & 1) * 1024;
#pragma unroll
        for (int mi = 0; mi < 4; ++mi) {
            bf16x4 pk;
#pragma unroll
            for (int rg = 0; rg < 4; ++rg) pk[rg] = (bf16_t)s[mi][rg];
            *(bf16x4*)(Pl + c * 64 + (((2 * mi + (g >> 1)) ^ (c & 7)) << 3) + 4 * (g & 1)) = pk;
        }

        // O^T = V^T P^T : lane(c,g) -> O^T[dh=16mi+4g+rg][tok=16ni+c]
        f32x4 o0 = z4, o1 = z4;
#pragma unroll
        for (int ks = 0; ks < 2; ++ks) {
            bf16x8 pa = *(const bf16x8*)(Pl + c * 64 + (((4 * ks + g) ^ (c & 7)) << 3));
            o0 = MFMA_BF16(vbA[ks][0], pa, o0);
            o1 = MFMA_BF16(vbA[ks][1], pa, o1);
        }
        // normalize (inv is per q-row = per (ni,c): uniform over g) + ao write
        int tok = 16 * ni + c;
#pragma unroll
        for (int mi = 0; mi < 2; ++mi) {
            f32x4 ov = (mi == 0) ? o0 : o1;
            bf16x4 pk;
#pragma unroll
            for (int rg = 0; rg < 4; ++rg) pk[rg] = (bf16_t)(ov[rg] * inv);
            int ci = h * 4 + mi * 2 + (g >> 1);
            *(bf16x4*)((char*)AO_s + tok * 512 + ((ci ^ (tok & 31)) << 4) + (g & 1) * 8) = pk;
        }
    }
    __syncthreads();

    // GEMM2: out[64 tok][256] = ao @ woutT^T + b_out. Wave wv owns 32 cols.
    f32x4 acc2[4][2];
#pragma unroll
    for (int i = 0; i < 4; ++i) { acc2[i][0] = z4; acc2[i][1] = z4; }

    for (int ks = 0; ks < 8; ++ks) {
        bf16x8 af2[4], bf2[2];
#pragma unroll
        for (int mi = 0; mi < 4; ++mi) {
            int rr = 16 * mi + c;
            af2[mi] = *(const bf16x8*)((char*)AO_s + rr * 512 + (((4 * ks + g) ^ (rr & 31)) << 4));
        }
#pragma unroll
        for (int nj = 0; nj < 2; ++nj)
            bf2[nj] = *(const bf16x8*)(woutT + (size_t)(32 * wv + 16 * nj + c) * 256 + 32 * ks + 8 * g);
#pragma unroll
        for (int mi = 0; mi < 4; ++mi)
#pragma unroll
            for (int nj = 0; nj < 2; ++nj)
                acc2[mi][nj] = MFMA_BF16(af2[mi], bf2[nj], acc2[mi][nj]);
    }

#pragma unroll
    for (int nj = 0; nj < 2; ++nj) {
        int gcol = 32 * wv + 16 * nj + c;
        float bo = b_out[gcol];
#pragma unroll
        for (int mi = 0; mi < 4; ++mi)
#pragma unroll
            for (int rg = 0; rg < 4; ++rg) {
                int tok = 16 * mi + 4 * g + rg;
                size_t r = (size_t)(rbase + (tok >> 3) * 256 + (tok & 7));
                out[r * 256 + gcol] = acc2[mi][nj][rg] + bo;
            }
    }
}

// ---------------------------------------------------------------------------
extern "C" void kernel_launch(void* const* d_in, const int* in_sizes, int n_in,
                              void* d_out, int out_size, void* d_ws, size_t ws_size,
                              hipStream_t stream) {
    const float* x       = (const float*)d_in[0];
    const float* w_qkv   = (const float*)d_in[1];
    const float* pos_emb = (const float*)d_in[2];
    const float* w_out   = (const float*)d_in[3];
    const float* b_out   = (const float*)d_in[4];
    const int*   rel_idx = (const int*)d_in[5];

    char* ws = (char*)d_ws;
    bf16_t* wqkvT = (bf16_t*)(ws + WQKVT_OFF);
    bf16_t* woutT = (bf16_t*)(ws + WOUTT_OFF);
    float*  biasP = (float*)(ws + BIASP_OFF);
    bf16_t* qkv   = (bf16_t*)(ws + QKV_OFF);   // ~192.5MB of ws
    float*  out   = (float*)d_out;

    prep_kernel<<<1040, 256, 0, stream>>>(w_qkv, w_out, pos_emb, rel_idx,
                                          wqkvT, woutT, biasP);
    qkvproj_kernel<<<1024, 256, 0, stream>>>(x, wqkvT, qkv);
    attn_out_kernel<<<2048, 512, 0, stream>>>(qkv, biasP, woutT, b_out, out);
}

// Round 5
// 216.553 us; speedup vs baseline: 1.7876x; 1.0390x over previous
//
#include <hip/hip_runtime.h>

// ---------------------------------------------------------------------------
// BaseWindowAttention on MI355X (gfx950) — fused 3-kernel pipeline
// x:[2,256,256,256]f32, w_qkv:[256,768]f32, pos_emb:[15,15]f32,
// w_out:[256,256]f32, b_out:[256]f32, rel_idx:[64,64,2]i32
// out:[2,256,256,256]f32
//
//  prep:     w_qkv^T, w_out^T -> bf16 (ws), biasP[lane][64] f32 (ws)
//  qkvproj:  fused x->bf16 + qkv GEMM. Block = 128 rows; x staged ONCE into
//            a chunk-XOR'd 64KB LDS tile; B double-buffered (2x8KB), one
//            barrier per K-step (stage issued before compute).
//  attn_out: fused window attention + output projection. Block = 1 window,
//            8 waves (1 head each). P aliased onto the V^T buffer (V frags
//            hoisted to regs first; per-wave DS ops are in-order) -> 64KB
//            LDS -> 2 blocks/CU.
// ---------------------------------------------------------------------------

typedef __bf16 bf16_t;
typedef __bf16 bf16x8 __attribute__((ext_vector_type(8)));
typedef __bf16 bf16x4 __attribute__((ext_vector_type(4)));
typedef float  f32x4  __attribute__((ext_vector_type(4)));

#define MFMA_BF16(a, b, c) __builtin_amdgcn_mfma_f32_16x16x32_bf16((a), (b), (c), 0, 0, 0)
#define SM_SCALE 0.17677669529663687f  // 32^-0.5

// ws layout (bytes)
#define WQKVT_OFF 0u          // bf16 [768][256]
#define WOUTT_OFF 393216u     // bf16 [256][256]
#define BIASP_OFF 524288u     // f32  [64 lanes][64]  (pre-permuted)
#define QKV_OFF   540672u     // bf16 [131072][768]

__device__ __forceinline__ void gload16(const void* g, void* l) {
    __builtin_amdgcn_global_load_lds(
        (const __attribute__((address_space(1))) unsigned int*)g,
        (__attribute__((address_space(3))) unsigned int*)l,
        16, 0, 0);
}

// ---------------------------------------------------------------------------
__global__ __launch_bounds__(256) void prep_kernel(
    const float* __restrict__ w_qkv, const float* __restrict__ w_out,
    const float* __restrict__ pos_emb, const int* __restrict__ rel_idx,
    bf16_t* __restrict__ wqkvT, bf16_t* __restrict__ woutT,
    float* __restrict__ biasP)
{
    int idx = blockIdx.x * 256 + threadIdx.x;
    if (idx < 196608) {                 // wqkvT[n][k] = w_qkv[k][n]
        int n = idx >> 8, k = idx & 255;
        wqkvT[idx] = (bf16_t)w_qkv[k * 768 + n];
    } else if (idx < 262144) {          // woutT[n][k] = w_out[k][n]
        int t = idx - 196608;
        int n = t >> 8, k = t & 255;
        woutT[t] = (bf16_t)w_out[k * 256 + n];
    } else if (idx < 266240) {          // biasP[lane][e]: per-lane MFMA layout
        int t = idx - 262144;
        int lane = t >> 6, e = t & 63;
        int ni = e >> 4, mi = (e >> 2) & 3, rg = e & 3;
        int i = 16 * ni + (lane & 15);          // query index
        int j = 16 * mi + 4 * (lane >> 4) + rg; // key index
        int i0 = rel_idx[(i * 64 + j) * 2 + 0];
        int i1 = rel_idx[(i * 64 + j) * 2 + 1];
        biasP[t] = pos_emb[i0 * 15 + i1];
    }
}

// ---------------------------------------------------------------------------
// Fused x-convert + qkv GEMM.
// C[M=131072][N=768] = bf16(x)[M][256] @ wT^T, C bf16.
// Block = 128 rows (grid 1024), 4 waves (2x2 of 64x64), BK=32.
// A resident in LDS (64KB, chunk-XOR). B double-buffered: stage(t+1) issued
// BEFORE compute(t); single barrier per K-step (min-2-phase schedule).
__global__ __launch_bounds__(256, 2) void qkvproj_kernel(
    const float* __restrict__ x, const bf16_t* __restrict__ wT,
    bf16_t* __restrict__ qkv)
{
    __shared__ __align__(16) bf16_t A_s[128 * 256];    // 64KB
    __shared__ __align__(16) bf16_t B_s[2][128 * 32];  // 2x8KB

    const int tid = threadIdx.x;
    const int lane = tid & 63, wv = tid >> 6;
    const int g = lane >> 4, c = lane & 15;
    const int wm = wv >> 1, wn = wv & 1;
    const int m0 = blockIdx.x << 7;
    f32x4 z4 = {0.f, 0.f, 0.f, 0.f};

    // stage B(t=0) early: overlaps the whole A-conversion phase
    {
#pragma unroll
        for (int i = 0; i < 2; ++i) {
            int q = i * 256 + tid;
            int row = q >> 2;
            int pl = (q & 3) ^ (row & 3);
            gload16(wT + row * 256 + pl * 8,
                    (char*)B_s[0] + (i * 256 + wv * 64) * 16);
        }
    }

    // phase 0: x (f32) -> bf16 into A_s, coalesced 32B/lane, XOR-chunked.
#pragma unroll
    for (int jj = 0; jj < 16; ++jj) {
        int q = jj * 512 + tid * 2;          // f32x4-chunk index (8192 total)
        int row = q >> 6;
        int ci = (q & 63) >> 1;              // 16B bf16-chunk 0..31
        const f32x4* xp = (const f32x4*)(x + (size_t)(m0 + row) * 256 + (q & 63) * 4);
        f32x4 a = xp[0], b = xp[1];
        bf16x8 t;
        t[0] = (bf16_t)a[0]; t[1] = (bf16_t)a[1];
        t[2] = (bf16_t)a[2]; t[3] = (bf16_t)a[3];
        t[4] = (bf16_t)b[0]; t[5] = (bf16_t)b[1];
        t[6] = (bf16_t)b[2]; t[7] = (bf16_t)b[3];
        *(bf16x8*)(A_s + row * 256 + ((ci ^ (row & 31)) << 3)) = t;
    }
    __syncthreads();   // drains B(0) vmcnt + A lgkm

    f32x4 acc[4][4];
    int cur = 0;
    for (int t = 0; t < 48; ++t) {           // t = bn*8 + ks
        const int ks = t & 7;
        // stage B(t+1) into the other buffer BEFORE compute
        if (t + 1 < 48) {
            int bn1 = (t + 1) >> 3, ks1 = (t + 1) & 7;
            int n01 = bn1 << 7;
#pragma unroll
            for (int i = 0; i < 2; ++i) {
                int q = i * 256 + tid;
                int row = q >> 2;
                int pl = (q & 3) ^ (row & 3);
                gload16(wT + (n01 + row) * 256 + ks1 * 32 + pl * 8,
                        (char*)B_s[cur ^ 1] + (i * 256 + wv * 64) * 16);
            }
        }
        if (ks == 0) {
#pragma unroll
            for (int i = 0; i < 4; ++i)
#pragma unroll
                for (int j = 0; j < 4; ++j) acc[i][j] = z4;
        }

        const f32x4* Bsf = (const f32x4*)B_s[cur];
        bf16x8 af[4], bfr[4];
#pragma unroll
        for (int mi = 0; mi < 4; ++mi) {
            int r = wm * 64 + mi * 16 + c;
            af[mi] = *(const bf16x8*)(A_s + r * 256 + (((4 * ks + g) ^ (r & 31)) << 3));
        }
#pragma unroll
        for (int ni = 0; ni < 4; ++ni) {
            int r2 = wn * 64 + ni * 16 + c;
            f32x4 tt = Bsf[r2 * 4 + (g ^ (r2 & 3))];
            bfr[ni] = __builtin_bit_cast(bf16x8, tt);
        }
#pragma unroll
        for (int mi = 0; mi < 4; ++mi)
#pragma unroll
            for (int ni = 0; ni < 4; ++ni)
                acc[mi][ni] = MFMA_BF16(af[mi], bfr[ni], acc[mi][ni]);

        if (ks == 7) {   // epilogue for column tile bn = t>>3
            int n0 = (t >> 3) << 7;
#pragma unroll
            for (int mi = 0; mi < 4; ++mi)
#pragma unroll
                for (int ni = 0; ni < 4; ++ni)
#pragma unroll
                    for (int rg = 0; rg < 4; ++rg) {
                        int grow = m0 + wm * 64 + mi * 16 + 4 * g + rg;
                        int gcol = n0 + wn * 64 + ni * 16 + c;
                        qkv[(size_t)grow * 768 + gcol] = (bf16_t)acc[mi][ni][rg];
                    }
        }
        __syncthreads();   // next buffer staged + everyone done with cur
        cur ^= 1;
    }
}

// ---------------------------------------------------------------------------
// Fused window attention + output projection. Grid 2048 (one per window),
// 512 threads = 8 waves = 8 heads. Swapped QK^T, in-register softmax,
// O^T = V^T P^T. P tile ALIASED onto the V^T buffer (V frags hoisted to
// registers before first P write; per-wave DS ops are in-order; shared base
// pointer blocks compiler reordering). 64KB LDS -> 2 blocks/CU.
__global__ __launch_bounds__(512, 2) void attn_out_kernel(
    const bf16_t* __restrict__ qkv, const float* __restrict__ biasP,
    const bf16_t* __restrict__ woutT, const float* __restrict__ b_out,
    float* __restrict__ out)
{
    __shared__ __align__(16) bf16_t PV_s[8][2048];   // 4KB/wave: Vt, then P
    __shared__ __align__(16) bf16_t AO_s[64 * 256];  // 32KB

    const int tid = threadIdx.x;
    const int lane = tid & 63, wv = tid >> 6;
    const int g = lane >> 4, c = lane & 15;
    const int b = blockIdx.x;
    const int h = wv;
    const int rbase = (b >> 10) * 65536 + ((b >> 5) & 31) * 2048 + (b & 31) * 8;

    bf16_t* Vw = PV_s[wv];
    bf16_t* Pw = PV_s[wv];   // alias (temporally disjoint per wave)
    const float* bp = biasP + lane * 64;
    f32x4 z4 = {0.f, 0.f, 0.f, 0.f};

    // K (A-frag) / Q (B-frag): 16B per lane straight from global.
    bf16x8 qf[4], kf[4];
#pragma unroll
    for (int mi = 0; mi < 4; ++mi) {
        int t = mi * 16 + c;
        size_t r = (size_t)(rbase + (t >> 3) * 256 + (t & 7));
        const bf16_t* rowp = qkv + r * 768 + h * 32;
        qf[mi] = *(const bf16x8*)(rowp + g * 8);
        kf[mi] = *(const bf16x8*)(rowp + 256 + g * 8);
    }
    // V -> Vt LDS (transposed, swizzled): Vt[dh][tok]
    {
        int t = lane;
        size_t r = (size_t)(rbase + (t >> 3) * 256 + (t & 7));
        const bf16_t* rowp = qkv + r * 768 + 512 + h * 32;
#pragma unroll
        for (int d0 = 0; d0 < 4; ++d0) {
            bf16x8 v = *(const bf16x8*)(rowp + d0 * 8);
#pragma unroll
            for (int j = 0; j < 8; ++j) {
                int dh = d0 * 8 + j;
                Vw[dh * 64 + ((((t >> 3) ^ (dh & 7)) << 3) | (t & 7))] = v[j];
            }
        }
    }
    // hoist V^T A-fragments to registers (Vw dead afterwards -> P reuses it)
    bf16x8 vbA[2][2];
#pragma unroll
    for (int ks = 0; ks < 2; ++ks)
#pragma unroll
        for (int mi = 0; mi < 2; ++mi) {
            int dh = mi * 16 + c;
            vbA[ks][mi] = *(const bf16x8*)(Vw + dh * 64 + (((4 * ks + g) ^ (dh & 7)) << 3));
        }

    // per-ni: QK^T -> softmax -> P tile -> O^T = V^T P^T -> ao LDS
#pragma unroll
    for (int ni = 0; ni < 4; ++ni) {
        f32x4 s[4];
        __builtin_amdgcn_s_setprio(1);
#pragma unroll
        for (int mi = 0; mi < 4; ++mi)
            s[mi] = MFMA_BF16(kf[mi], qf[ni], z4);
        __builtin_amdgcn_s_setprio(0);

        float mx = -1e30f;
#pragma unroll
        for (int mi = 0; mi < 4; ++mi) {
            f32x4 bb = *(const f32x4*)(bp + ni * 16 + mi * 4);
#pragma unroll
            for (int rg = 0; rg < 4; ++rg) {
                float t = fmaf(s[mi][rg], SM_SCALE, bb[rg]);
                s[mi][rg] = t;
                mx = fmaxf(mx, t);
            }
        }
        mx = fmaxf(mx, __shfl_xor(mx, 16));
        mx = fmaxf(mx, __shfl_xor(mx, 32));
        float sm = 0.f;
#pragma unroll
        for (int mi = 0; mi < 4; ++mi)
#pragma unroll
            for (int rg = 0; rg < 4; ++rg) {
                float p = __expf(s[mi][rg] - mx);
                s[mi][rg] = p;
                sm += p;
            }
        sm += __shfl_xor(sm, 16);
        sm += __shfl_xor(sm, 32);
        float inv = 1.0f / sm;

        bf16_t* Pl = Pw + (ni & 1) * 1024;
#pragma unroll
        for (int mi = 0; mi < 4; ++mi) {
            bf16x4 pk;
#pragma unroll
            for (int rg = 0; rg < 4; ++rg) pk[rg] = (bf16_t)s[mi][rg];
            *(bf16x4*)(Pl + c * 64 + (((2 * mi + (g >> 1)) ^ (c & 7)) << 3) + 4 * (g & 1)) = pk;
        }

        // O^T = V^T P^T : lane(c,g) -> O^T[dh=16mi+4g+rg][tok=16ni+c]
        f32x4 o0 = z4, o1 = z4;
        __builtin_amdgcn_s_setprio(1);
#pragma unroll
        for (int ks = 0; ks < 2; ++ks) {
            bf16x8 pa = *(const bf16x8*)(Pl + c * 64 + (((4 * ks + g) ^ (c & 7)) << 3));
            o0 = MFMA_BF16(vbA[ks][0], pa, o0);
            o1 = MFMA_BF16(vbA[ks][1], pa, o1);
        }
        __builtin_amdgcn_s_setprio(0);
        // normalize (inv is per q-row, uniform over g) + ao write (b64)
        int tok = 16 * ni + c;
#pragma unroll
        for (int mi = 0; mi < 2; ++mi) {
            f32x4 ov = (mi == 0) ? o0 : o1;
            bf16x4 pk;
#pragma unroll
            for (int rg = 0; rg < 4; ++rg) pk[rg] = (bf16_t)(ov[rg] * inv);
            int ci = h * 4 + mi * 2 + (g >> 1);
            *(bf16x4*)((char*)AO_s + tok * 512 + ((ci ^ (tok & 31)) << 4) + (g & 1) * 8) = pk;
        }
    }
    __syncthreads();

    // GEMM2: out[64 tok][256] = ao @ woutT^T + b_out. Wave wv owns 32 cols.
    f32x4 acc2[4][2];
#pragma unroll
    for (int i = 0; i < 4; ++i) { acc2[i][0] = z4; acc2[i][1] = z4; }

    for (int ks = 0; ks < 8; ++ks) {
        bf16x8 af2[4], bf2[2];
#pragma unroll
        for (int mi = 0; mi < 4; ++mi) {
            int rr = 16 * mi + c;
            af2[mi] = *(const bf16x8*)((char*)AO_s + rr * 512 + (((4 * ks + g) ^ (rr & 31)) << 4));
        }
#pragma unroll
        for (int nj = 0; nj < 2; ++nj)
            bf2[nj] = *(const bf16x8*)(woutT + (size_t)(32 * wv + 16 * nj + c) * 256 + 32 * ks + 8 * g);
#pragma unroll
        for (int mi = 0; mi < 4; ++mi)
#pragma unroll
            for (int nj = 0; nj < 2; ++nj)
                acc2[mi][nj] = MFMA_BF16(af2[mi], bf2[nj], acc2[mi][nj]);
    }

#pragma unroll
    for (int nj = 0; nj < 2; ++nj) {
        int gcol = 32 * wv + 16 * nj + c;
        float bo = b_out[gcol];
#pragma unroll
        for (int mi = 0; mi < 4; ++mi)
#pragma unroll
            for (int rg = 0; rg < 4; ++rg) {
                int tok = 16 * mi + 4 * g + rg;
                size_t r = (size_t)(rbase + (tok >> 3) * 256 + (tok & 7));
                out[r * 256 + gcol] = acc2[mi][nj][rg] + bo;
            }
    }
}

// ---------------------------------------------------------------------------
extern "C" void kernel_launch(void* const* d_in, const int* in_sizes, int n_in,
                              void* d_out, int out_size, void* d_ws, size_t ws_size,
                              hipStream_t stream) {
    const float* x       = (const float*)d_in[0];
    const float* w_qkv   = (const float*)d_in[1];
    const float* pos_emb = (const float*)d_in[2];
    const float* w_out   = (const float*)d_in[3];
    const float* b_out   = (const float*)d_in[4];
    const int*   rel_idx = (const int*)d_in[5];

    char* ws = (char*)d_ws;
    bf16_t* wqkvT = (bf16_t*)(ws + WQKVT_OFF);
    bf16_t* woutT = (bf16_t*)(ws + WOUTT_OFF);
    float*  biasP = (float*)(ws + BIASP_OFF);
    bf16_t* qkv   = (bf16_t*)(ws + QKV_OFF);   // ~192.5MB of ws
    float*  out   = (float*)d_out;

    prep_kernel<<<1040, 256, 0, stream>>>(w_qkv, w_out, pos_emb, rel_idx,
                                          wqkvT, woutT, biasP);
    qkvproj_kernel<<<1024, 256, 0, stream>>>(x, wqkvT, qkv);
    attn_out_kernel<<<2048, 512, 0, stream>>>(qkv, biasP, woutT, b_out, out);
}